// Round 1
// baseline (2755.234 us; speedup 1.0000x reference)
//
#include <hip/hip_runtime.h>

// Neural SDE rollout, split-K across blocks, register-resident weights.
// Geometry change vs prior round: 32 groups x 32 rows (2 M-tiles), 8 blocks
// per group (64-col H-slice each) -> 256 blocks, EXACTLY 1 block/CU
// (8 waves, 2/SIMD, VGPR-bound). All weight fragments (W1 slice, W2_mu tile,
// W2_sg 8 tiles) preloaded into VGPRs once -> zero steady-state L2 weight
// traffic (was ~640 KB/CU/step). Exchange algorithm identical to the
// validated R3/R4 scheme (3-slot atomicAdd rotation + release counter),
// only resized to 2048 floats/group; 1 block/CU removes the co-resident
// partner jitter that amplified per-step stragglers.

typedef _Float16 f16x8 __attribute__((ext_vector_type(8)));
typedef float    f32x4 __attribute__((ext_vector_type(4)));

#define MFMA(a,b,c) __builtin_amdgcn_mfma_f32_16x16x32_f16(a,b,c,0,0,0)

#define Bb 1024
#define Tt 128
#define NG 32          // groups
#define GB 8           // blocks per group (split-K over H=512 -> 64 cols each)
#define Rr 32          // rows per group (two MFMA M-tiles)
#define NT 512         // threads per block (8 waves)

// packed fragment regions in d_ws (units: halves) -- identical pack to R3/R4
#define W2SG_OFF 0
#define W2SG_HALVES (64*16*2*512)
#define W2MU_OFF (W2SG_OFF + W2SG_HALVES)
#define W2MU_HALVES (4*16*2*512)
#define W1MU_OFF (W2MU_OFF + W2MU_HALVES)
#define W1_HALVES (32*3*2*512)
#define W1SG_OFF (W1MU_OFF + W1_HALVES)
#define WS_HALVES (W1SG_OFF + W1_HALVES)
#define ACC_BYTES_OFF ((size_t)WS_HALVES * 2)
#define ACC_FLOATS (3 * NG * Rr * 64)     // 3 slots x 32 groups x 32x64
#define CNT_BYTES_OFF (ACC_BYTES_OFF + (size_t)ACC_FLOATS * 4)
#define CNT_STRIDE 16                     // pad counters to 64 B

__global__ __launch_bounds__(256) void pack_weights(
    const float* __restrict__ W1_mu, const float* __restrict__ W2_mu,
    const float* __restrict__ W1_sg, const float* __restrict__ W2_sg,
    _Float16* __restrict__ wsh)
{
    int gid = blockIdx.x * 256 + threadIdx.x;
    if (gid >= 81920) return;
    const float* src; int ncols, kvalid; size_t dst;
    int id, tile, ks, lane;
    if (gid < 65536) {                 // W2_sg: 64 tiles x 16 ks x 64 lanes
        id = gid; tile = id >> 10; id &= 1023; ks = id >> 6; lane = id & 63;
        src = W2_sg; ncols = 1024; kvalid = 512;
        dst = W2SG_OFF + (size_t)((tile*16 + ks)*2) * 512 + lane*8;
    } else if (gid < 69632) {          // W2_mu: 4 x 16 x 64
        id = gid - 65536; tile = id >> 10; id &= 1023; ks = id >> 6; lane = id & 63;
        src = W2_mu; ncols = 64; kvalid = 512;
        dst = W2MU_OFF + (size_t)((tile*16 + ks)*2) * 512 + lane*8;
    } else if (gid < 75776) {          // W1_mu: 32 tiles x 3 ks x 64
        id = gid - 69632; tile = id / 192; id %= 192; ks = id >> 6; lane = id & 63;
        src = W1_mu; ncols = 512; kvalid = 80;
        dst = W1MU_OFF + (size_t)((tile*3 + ks)*2) * 512 + lane*8;
    } else {                           // W1_sg
        id = gid - 75776; tile = id / 192; id %= 192; ks = id >> 6; lane = id & 63;
        src = W1_sg; ncols = 512; kvalid = 80;
        dst = W1SG_OFF + (size_t)((tile*3 + ks)*2) * 512 + lane*8;
    }
    const int n  = tile*16 + (lane & 15);
    const int kb = ks*32 + ((lane >> 4) << 3);
    f16x8 hi8, lo8;
    #pragma unroll
    for (int jj = 0; jj < 8; ++jj) {
        int k = kb + jj;
        float wv = (k < kvalid) ? src[(size_t)k * ncols + n] : 0.f;
        _Float16 h = (_Float16)wv;
        hi8[jj] = h;
        lo8[jj] = (_Float16)(wv - (float)h);
    }
    *((f16x8*)(wsh + dst))       = hi8;
    *((f16x8*)(wsh + dst + 512)) = lo8;
}

__global__ __launch_bounds__(NT, 2) void nsde_regw(
    const float* __restrict__ y0, const float* __restrict__ controls,
    const float* __restrict__ noise,
    const float* __restrict__ b1_mu, const float* __restrict__ b2_mu,
    const float* __restrict__ b1_sg, const float* __restrict__ b2_sg,
    const _Float16* __restrict__ wf,
    float* __restrict__ accbuf, unsigned int* __restrict__ cnt,
    float* __restrict__ out)
{
    __shared__ _Float16 s_xhi[Rr][104], s_xlo[Rr][104];     // x, K=96 (+pad)
    __shared__ _Float16 s_hhi[2][Rr][72], s_hlo[2][Rr][72]; // h slices (64+pad)
    __shared__ float s_y[Rr*64];     // [r*64+n]
    __shared__ float s_dw[Rr][16];
    __shared__ float s_part[Rr*64];  // sg partial (dW-folded)
    __shared__ float s_pmu[Rr*64];   // mu partial (*dt)

    const int tid  = threadIdx.x;
    const int lane = tid & 63, w = tid >> 6;
    const int m15  = lane & 15, quad = lane >> 4;
    const int j    = blockIdx.x & 7;        // K-slice id
    const int g    = blockIdx.x >> 3;       // group
    const int r0   = g * Rr;

    // per-wave constants
    const int l  = w >> 2;                  // GEMM1 layer: 0=mu 1=sg
    const int ct = w & 3;                   // GEMM1 col-tile within slice
    const int tg = j*4 + ct;                // global W1 H-tile
    const float bias1 = (l ? b1_sg : b1_mu)[j*64 + ct*16 + m15];
    float b2v[8];
    #pragma unroll
    for (int t = 0; t < 8; ++t)
        b2v[t] = (j == 0) ? b2_sg[(w + t*8)*16 + m15] : 0.f;
    const float b2m = (w < 4 && j == 0) ? b2_mu[w*16 + m15] * 0.01f : 0.f;

    // ---- preload ALL weight fragments into registers (live across T loop)
    f16x8 w1h[3], w1l[3];
    {
        const _Float16* w1base = wf + (l ? W1SG_OFF : W1MU_OFF);
        #pragma unroll
        for (int ks = 0; ks < 3; ++ks) {
            const _Float16* bp = w1base + (size_t)((tg*3 + ks)*2)*512 + lane*8;
            w1h[ks] = *(const f16x8*)bp;
            w1l[ks] = *(const f16x8*)(bp + 512);
        }
    }
    f16x8 wsg[8][4];
    #pragma unroll
    for (int t = 0; t < 8; ++t) {
        const _Float16* bp = wf + W2SG_OFF
            + (size_t)(((w + t*8)*16 + 2*j)*2)*512 + lane*8;
        wsg[t][0] = *(const f16x8*)(bp);
        wsg[t][1] = *(const f16x8*)(bp + 512);
        wsg[t][2] = *(const f16x8*)(bp + 1024);
        wsg[t][3] = *(const f16x8*)(bp + 1536);
    }
    f16x8 wmu[4];
    {
        const int wm = w & 3;   // waves >=4 load a valid (unused) tile
        const _Float16* bp = wf + W2MU_OFF
            + (size_t)((wm*16 + 2*j)*2)*512 + lane*8;
        wmu[0] = *(const f16x8*)(bp);
        wmu[1] = *(const f16x8*)(bp + 512);
        wmu[2] = *(const f16x8*)(bp + 1024);
        wmu[3] = *(const f16x8*)(bp + 1536);
    }

    // ---- init
    for (int e = tid; e < Rr*24; e += NT) {   // zero x K-pad cols 80..103
        int r = e / 24, c = 80 + e % 24;
        s_xhi[r][c] = (_Float16)0.f; s_xlo[r][c] = (_Float16)0.f;
    }
    {
        const int e0 = tid*4, r = e0 >> 6, n = e0 & 63;
        float4 yv = *(const float4*)&y0[(size_t)(r0 + r)*64 + n];
        float vv[4] = {yv.x, yv.y, yv.z, yv.w};
        #pragma unroll
        for (int q = 0; q < 4; ++q) {
            s_y[e0+q] = vv[q];
            _Float16 h = (_Float16)vv[q];
            s_xhi[r][n+q] = h; s_xlo[r][n+q] = (_Float16)(vv[q] - (float)h);
        }
        if ((tid >> 6) == j)                  // block j writes its 1/8 chunk
            *(float4*)&out[(size_t)(r0 + r)*64 + n] = yv;
        const int r2 = tid >> 4, c2 = tid & 15;
        float u = controls[c2];
        _Float16 h = (_Float16)u;
        s_xhi[r2][64+c2] = h; s_xlo[r2][64+c2] = (_Float16)(u - (float)h);
        s_dw[r2][c2] = noise[(size_t)(r0 + r2)*16 + c2] * 0.1f;
    }
    __syncthreads();

    for (int k = 0; k < Tt-1; ++k) {
        // ======== GEMM1: one 16-col tile per wave per layer, 2 M-tiles
        #pragma unroll
        for (int mt = 0; mt < 2; ++mt) {
            f32x4 a0 = {0,0,0,0}, a1 = {0,0,0,0}, a2 = {0,0,0,0};
            #pragma unroll
            for (int ks = 0; ks < 3; ++ks) {
                f16x8 ah = *(const f16x8*)&s_xhi[mt*16 + m15][ks*32 + quad*8];
                f16x8 al = *(const f16x8*)&s_xlo[mt*16 + m15][ks*32 + quad*8];
                a0 = MFMA(ah, w1h[ks], a0);
                a1 = MFMA(ah, w1l[ks], a1);
                a2 = MFMA(al, w1h[ks], a2);
            }
            f32x4 s = a0 + a1 + a2;
            #pragma unroll
            for (int rg = 0; rg < 4; ++rg) {
                int row = mt*16 + quad*4 + rg;
                float v = fmaxf(s[rg] + bias1, 0.f);
                _Float16 h = (_Float16)v;
                s_hhi[l][row][ct*16 + m15] = h;
                s_hlo[l][row][ct*16 + m15] = (_Float16)(v - (float)h);
            }
        }
        // prefetch next-step controls/noise into regs (latency hidden by GEMM2)
        float u_nx = 0.f, dw_nx = 0.f;
        const int r2 = tid >> 4, c2 = tid & 15;
        if (k < Tt-2) {
            u_nx  = controls[(size_t)(k+1)*16 + c2];
            dw_nx = noise[((size_t)(k+1)*Bb + r0 + r2)*16 + c2] * 0.1f;
        }
        __syncthreads();

        // ======== GEMM2 over this block's K-slice (local k in [0,64))
        #pragma unroll
        for (int mt = 0; mt < 2; ++mt) {
            const int rb = mt*16;
            float dwv[4];
            #pragma unroll
            for (int rg = 0; rg < 4; ++rg)
                dwv[rg] = s_dw[rb + quad*4 + rg][m15];

            // -- mu partial (waves 0..3 take n-tile w)
            if (w < 4) {
                f16x8 Mh0 = *(const f16x8*)&s_hhi[0][rb + m15][quad*8];
                f16x8 Ml0 = *(const f16x8*)&s_hlo[0][rb + m15][quad*8];
                f16x8 Mh1 = *(const f16x8*)&s_hhi[0][rb + m15][32 + quad*8];
                f16x8 Ml1 = *(const f16x8*)&s_hlo[0][rb + m15][32 + quad*8];
                f32x4 hh = {0,0,0,0}, hl = {0,0,0,0}, lh = {0,0,0,0};
                hh = MFMA(Mh0, wmu[0], hh); hl = MFMA(Mh0, wmu[1], hl);
                lh = MFMA(Ml0, wmu[0], lh);
                hh = MFMA(Mh1, wmu[2], hh); hl = MFMA(Mh1, wmu[3], hl);
                lh = MFMA(Ml1, wmu[2], lh);
                f32x4 s = hh + hl + lh;
                #pragma unroll
                for (int rg = 0; rg < 4; ++rg)
                    s_pmu[(rb + quad*4 + rg)*64 + w*16 + m15] = s[rg]*0.01f + b2m;
            }

            // -- sg partials: 8 n-tiles per wave, weights in VGPRs
            f16x8 Ah0 = *(const f16x8*)&s_hhi[1][rb + m15][quad*8];
            f16x8 Al0 = *(const f16x8*)&s_hlo[1][rb + m15][quad*8];
            f16x8 Ah1 = *(const f16x8*)&s_hhi[1][rb + m15][32 + quad*8];
            f16x8 Al1 = *(const f16x8*)&s_hlo[1][rb + m15][32 + quad*8];
            #pragma unroll
            for (int t = 0; t < 8; ++t) {
                const int nt = w + t*8;
                f32x4 hh = {0,0,0,0}, hl = {0,0,0,0}, lh = {0,0,0,0};
                hh = MFMA(Ah0, wsg[t][0], hh); hl = MFMA(Ah0, wsg[t][1], hl);
                lh = MFMA(Al0, wsg[t][0], lh);
                hh = MFMA(Ah1, wsg[t][2], hh); hl = MFMA(Ah1, wsg[t][3], hl);
                lh = MFMA(Al1, wsg[t][2], lh);
                f32x4 s = hh + hl + lh;
                #pragma unroll
                for (int rg = 0; rg < 4; ++rg) {
                    float v = (s[rg] + b2v[t]) * dwv[rg];
                    v += __shfl_xor(v, 1); v += __shfl_xor(v, 2);
                    v += __shfl_xor(v, 4); v += __shfl_xor(v, 8);
                    if (m15 == 0) s_part[(rb + quad*4 + rg)*64 + nt] = v;
                }
            }
        }
        __syncthreads();

        // ======== exchange: atomicAdd partials into slot k%3
        const int slot = k % 3;
        float* ab = accbuf + ((size_t)slot*NG + g)*(Rr*64);
        const int e0 = tid*4;
        #pragma unroll
        for (int q = 0; q < 4; ++q) {
            float v = s_part[e0+q] + s_pmu[e0+q];
            __hip_atomic_fetch_add(&ab[e0+q], v, __ATOMIC_RELAXED,
                                   __HIP_MEMORY_SCOPE_AGENT);
        }
        __syncthreads();   // drains vmcnt: all adds complete
        if (tid == 0) {
            __hip_atomic_fetch_add(&cnt[g*CNT_STRIDE], 1u, __ATOMIC_RELEASE,
                                   __HIP_MEMORY_SCOPE_AGENT);
            while (__hip_atomic_load(&cnt[g*CNT_STRIDE], __ATOMIC_RELAXED,
                                     __HIP_MEMORY_SCOPE_AGENT) < (unsigned)GB*(k+1))
                __builtin_amdgcn_s_sleep(2);
        }
        __syncthreads();

        // ======== read sum, y update, out write, next x/dW build
        {
            const int r = e0 >> 6, n = e0 & 63;
            float yn[4];
            #pragma unroll
            for (int q = 0; q < 4; ++q) {
                float sum = __hip_atomic_load(&ab[e0+q], __ATOMIC_RELAXED,
                                              __HIP_MEMORY_SCOPE_AGENT);
                yn[q] = s_y[e0+q] + sum;
                s_y[e0+q] = yn[q];
                _Float16 h = (_Float16)yn[q];
                s_xhi[r][n+q] = h;
                s_xlo[r][n+q] = (_Float16)(yn[q] - (float)h);
            }
            if ((tid >> 6) == j) {   // wave j writes this block's 256-elem chunk
                float4 o = {yn[0], yn[1], yn[2], yn[3]};
                *(float4*)&out[((size_t)(k+1)*Bb + r0 + r)*64 + n] = o;
                if (k >= 1) {        // zero slot (k-1)%3 (3-slot rotation safe)
                    float* zb = accbuf + ((size_t)((k-1)%3)*NG + g)*(Rr*64);
                    #pragma unroll
                    for (int q = 0; q < 4; ++q)
                        __hip_atomic_store(&zb[e0+q], 0.f, __ATOMIC_RELAXED,
                                           __HIP_MEMORY_SCOPE_AGENT);
                }
            }
        }
        if (k < Tt-2) {
            _Float16 h = (_Float16)u_nx;
            s_xhi[r2][64+c2] = h; s_xlo[r2][64+c2] = (_Float16)(u_nx - (float)h);
            s_dw[r2][c2] = dw_nx;
        }
        __syncthreads();
    }
}

extern "C" void kernel_launch(void* const* d_in, const int* in_sizes, int n_in,
                              void* d_out, int out_size, void* d_ws, size_t ws_size,
                              hipStream_t stream) {
    const float* y0       = (const float*)d_in[0];
    const float* controls = (const float*)d_in[1];
    const float* noise    = (const float*)d_in[2];
    const float* W1_mu    = (const float*)d_in[3];
    const float* b1_mu    = (const float*)d_in[4];
    const float* W2_mu    = (const float*)d_in[5];
    const float* b2_mu    = (const float*)d_in[6];
    const float* W1_sg    = (const float*)d_in[7];
    const float* b1_sg    = (const float*)d_in[8];
    const float* W2_sg    = (const float*)d_in[9];
    const float* b2_sg    = (const float*)d_in[10];
    float* out = (float*)d_out;
    _Float16* wsh = (_Float16*)d_ws;
    float* accbuf = (float*)((char*)d_ws + ACC_BYTES_OFF);
    unsigned int* cnt = (unsigned int*)((char*)d_ws + CNT_BYTES_OFF);

    // zero accumulator slots + padded counters (ws is poisoned 0xAA each call)
    hipMemsetAsync((char*)d_ws + ACC_BYTES_OFF, 0,
                   (size_t)ACC_FLOATS*4 + (size_t)NG*CNT_STRIDE*4, stream);
    pack_weights<<<320, 256, 0, stream>>>(W1_mu, W2_mu, W1_sg, W2_sg, wsh);
    nsde_regw<<<NG*GB, NT, 0, stream>>>(y0, controls, noise,
                                        b1_mu, b2_mu, b1_sg, b2_sg,
                                        (const _Float16*)wsh,
                                        accbuf, cnt, out);
}